// Round 13
// baseline (626.182 us; speedup 1.0000x reference)
//
#include <hip/hip_runtime.h>
#include <math.h>

#define N_NODES 50000
#define N_EDGES 1600000
#define DIM 128          // D == H == 128
#define EPS 1e-5f
#define CAP 96           // bucket capacity; P(Poisson(32) >= 96) ~ 1e-18/bucket
#define CONVB 2048       // convert blocks in the specialized kernel

typedef short bf16x8 __attribute__((ext_vector_type(8)));
typedef float f32x4 __attribute__((ext_vector_type(4)));
typedef int i32x4 __attribute__((ext_vector_type(4)));
typedef unsigned int u32x2 __attribute__((ext_vector_type(2)));
typedef unsigned short ushort_t;

// fp32 -> bf16 round-to-nearest-even
__device__ __forceinline__ unsigned int f2bf(float f) {
    unsigned int u = __float_as_uint(f);
    return (u + 0x7FFFu + ((u >> 16) & 1u)) >> 16;
}
__device__ __forceinline__ float bf2f(ushort_t u) {
    return __uint_as_float(((unsigned int)u) << 16);
}
// unpack a word of 2 bf16 and max into (lo, hi) floats
__device__ __forceinline__ void wmax(unsigned int w, float& lo, float& hi) {
    lo = fmaxf(lo, __uint_as_float(w << 16));
    hi = fmaxf(hi, __uint_as_float(w & 0xFFFF0000u));
}

// ---------------- A: weights -> bf16 transposed; zero stats + cnt ----------------
__global__ __launch_bounds__(256) void k_prep(const float* __restrict__ W1, const float* __restrict__ W2,
                                              ushort_t* __restrict__ W1t, ushort_t* __restrict__ W2t,
                                              float* __restrict__ stats, int* __restrict__ cnt) {
    int gid = blockIdx.x * 256 + threadIdx.x;
    if (gid < 128 * 384) {
        int j = gid / 384, k = gid % 384;
        W1t[gid] = (ushort_t)f2bf(W1[k * 128 + j]);
    } else if (gid < 128 * 384 + 128 * 128) {
        int g2 = gid - 128 * 384;
        int j = g2 / 128, k = g2 % 128;
        W2t[g2] = (ushort_t)f2bf(W2[k * 128 + j]);
    }
    if (gid < 512) stats[gid] = 0.0f;
    if (gid < 2 * N_NODES) cnt[gid] = 0;
}

// ---------------- B: BLOCK-SPECIALIZED bucket (odd blocks) + convert (even blocks) ----------------
// Latency-bound binning and BW-bound convert co-resident -> true overlap.
__global__ __launch_bounds__(256) void k_bucketconv(const int* __restrict__ ei, int* __restrict__ cnt,
                                                    int* __restrict__ slots,
                                                    const f32x4* __restrict__ msg,
                                                    u32x2* __restrict__ msgb) {
    const int b = blockIdx.x;
    if (b & 1) {
        // ---- binning: odd blocks. nt stores: slot entries are write-once/read-once,
        // don't let them thrash per-XCD L2 during the overlapped convert.
        int t = (b >> 1) * 256 + threadIdx.x;
        if (t >= N_EDGES / 4) return;
        int4 r4 = reinterpret_cast<const int4*>(ei)[t];
        int4 c4 = reinterpret_cast<const int4*>(ei + N_EDGES)[t];
        int e = t * 4;
        __builtin_nontemporal_store(e + 0, &slots[c4.x * CAP + atomicAdd(&cnt[c4.x], 1)]);
        __builtin_nontemporal_store(e + 1, &slots[c4.y * CAP + atomicAdd(&cnt[c4.y], 1)]);
        __builtin_nontemporal_store(e + 2, &slots[c4.z * CAP + atomicAdd(&cnt[c4.z], 1)]);
        __builtin_nontemporal_store(e + 3, &slots[c4.w * CAP + atomicAdd(&cnt[c4.w], 1)]);
        __builtin_nontemporal_store(e + 0, &slots[(N_NODES + r4.x) * CAP + atomicAdd(&cnt[N_NODES + r4.x], 1)]);
        __builtin_nontemporal_store(e + 1, &slots[(N_NODES + r4.y) * CAP + atomicAdd(&cnt[N_NODES + r4.y], 1)]);
        __builtin_nontemporal_store(e + 2, &slots[(N_NODES + r4.z) * CAP + atomicAdd(&cnt[N_NODES + r4.z], 1)]);
        __builtin_nontemporal_store(e + 3, &slots[(N_NODES + r4.w) * CAP + atomicAdd(&cnt[N_NODES + r4.w], 1)]);
    } else {
        // ---- convert: even blocks (streaming, coalesced)
        const int cb = b >> 1;
        const size_t total = (size_t)N_EDGES * 32;   // f32x4 vectors
        const size_t stride = (size_t)CONVB * 256;
        for (size_t v = (size_t)cb * 256 + threadIdx.x; v < total; v += stride) {
            f32x4 m = __builtin_nontemporal_load(&msg[v]);
            u32x2 o;
            o[0] = f2bf(m[0]) | (f2bf(m[1]) << 16);
            o[1] = f2bf(m[2]) | (f2bf(m[3]) << 16);
            msgb[v] = o;   // regular store: leave lines in L2/L3 for the gather
        }
    }
}

// ---------------- C: gather-max over bf16 rows; 8 rows in flight per half-wave ----------------
__global__ __launch_bounds__(256) void k_gather(const u32x2* __restrict__ msgb,
                                                const int* __restrict__ slots,
                                                const int* __restrict__ cnt,
                                                ushort_t* __restrict__ fwd,
                                                ushort_t* __restrict__ bwd) {
    const int wid = blockIdx.x * 4 + (threadIdx.x >> 6);   // 0 .. 2N-1
    const int dir = wid & 1;                               // interleave fwd/bwd in time
    const int n = wid >> 1;
    const int lane = threadIdx.x & 63;
    const int q = lane & 31;        // channel quad: channels q*4..q*4+3 (one u32x2)
    const int h = lane >> 5;        // half-wave id
    const int c = cnt[dir * N_NODES + n];
    const int* el = slots + (size_t)(dir * N_NODES + n) * CAP;

    float l0a = -INFINITY, h0a = -INFINITY, l1a = -INFINITY, h1a = -INFINITY;
    float l0b = -INFINITY, h0b = -INFINITY, l1b = -INFINITY, h1b = -INFINITY;
    const int nfull = c >> 2;
    int g = h;
    // 2 groups (8 rows) in flight per half-wave
    for (; g + 2 < nfull; g += 4) {
        i32x4 ea = *reinterpret_cast<const i32x4*>(el + g * 4);
        i32x4 eb = *reinterpret_cast<const i32x4*>(el + (g + 2) * 4);
        u32x2 m0 = msgb[(size_t)ea[0] * 32 + q];
        u32x2 m1 = msgb[(size_t)ea[1] * 32 + q];
        u32x2 m2 = msgb[(size_t)ea[2] * 32 + q];
        u32x2 m3 = msgb[(size_t)ea[3] * 32 + q];
        u32x2 m4 = msgb[(size_t)eb[0] * 32 + q];
        u32x2 m5 = msgb[(size_t)eb[1] * 32 + q];
        u32x2 m6 = msgb[(size_t)eb[2] * 32 + q];
        u32x2 m7 = msgb[(size_t)eb[3] * 32 + q];
        wmax(m0[0], l0a, h0a); wmax(m0[1], l1a, h1a);
        wmax(m1[0], l0a, h0a); wmax(m1[1], l1a, h1a);
        wmax(m2[0], l0a, h0a); wmax(m2[1], l1a, h1a);
        wmax(m3[0], l0a, h0a); wmax(m3[1], l1a, h1a);
        wmax(m4[0], l0b, h0b); wmax(m4[1], l1b, h1b);
        wmax(m5[0], l0b, h0b); wmax(m5[1], l1b, h1b);
        wmax(m6[0], l0b, h0b); wmax(m6[1], l1b, h1b);
        wmax(m7[0], l0b, h0b); wmax(m7[1], l1b, h1b);
    }
    for (; g < nfull; g += 2) {
        i32x4 e4 = *reinterpret_cast<const i32x4*>(el + g * 4);
        u32x2 m0 = msgb[(size_t)e4[0] * 32 + q];
        u32x2 m1 = msgb[(size_t)e4[1] * 32 + q];
        u32x2 m2 = msgb[(size_t)e4[2] * 32 + q];
        u32x2 m3 = msgb[(size_t)e4[3] * 32 + q];
        wmax(m0[0], l0a, h0a); wmax(m0[1], l1a, h1a);
        wmax(m1[0], l0a, h0a); wmax(m1[1], l1a, h1a);
        wmax(m2[0], l0a, h0a); wmax(m2[1], l1a, h1a);
        wmax(m3[0], l0a, h0a); wmax(m3[1], l1a, h1a);
    }
    if (h == (nfull & 1)) {
        for (int p = nfull * 4; p < c; ++p) {
            u32x2 m = msgb[(size_t)el[p] * 32 + q];
            wmax(m[0], l0b, h0b); wmax(m[1], l1b, h1b);
        }
    }
    float l0 = fmaxf(l0a, l0b), h0 = fmaxf(h0a, h0b);
    float l1 = fmaxf(l1a, l1b), h1 = fmaxf(h1a, h1b);
    l0 = fmaxf(l0, __shfl_xor(l0, 32));
    h0 = fmaxf(h0, __shfl_xor(h0, 32));
    l1 = fmaxf(l1, __shfl_xor(l1, 32));
    h1 = fmaxf(h1, __shfl_xor(h1, 32));

    if (h == 0) {
        u32x2 o;
        if (c == 0) { o[0] = 0u; o[1] = 0u; }   // empty segment -> 0
        else {
            o[0] = (__float_as_uint(l0) >> 16) | (__float_as_uint(h0) & 0xFFFF0000u);
            o[1] = (__float_as_uint(l1) >> 16) | (__float_as_uint(h1) & 0xFFFF0000u);
        }
        *reinterpret_cast<u32x2*>((dir ? bwd : fwd) + n * DIM + q * 4) = o;
    }
}

// ======== MFMA GEMM core (64 rows x 128 cols per block, 4 waves, 16x16x32 bf16) ========
// LDS tiles XOR-swizzled: byte ^= ((row&7)<<4).

// ---------------- D: h1b = bf16([x|fwd|bwd] @ W1 + b1), col stats ----------------
__global__ __launch_bounds__(256) void k_gemm1(const float* __restrict__ x,
                                               const ushort_t* __restrict__ fwd,
                                               const ushort_t* __restrict__ bwd,
                                               const ushort_t* __restrict__ W1t,
                                               const float* __restrict__ b1,
                                               ushort_t* __restrict__ h1b,
                                               float* __restrict__ stats) {
    __shared__ uint4 rowsA4[512];      // 64 rows x 64 k bf16 (8 KB), swizzled
    __shared__ uint4 Wt4[1024];        // 128 j x 64 k bf16 (16 KB), swizzled
    __shared__ float bias[128];
    __shared__ float s_sum[128], s_sq[128];
    char* rowsA = (char*)rowsA4;
    char* Wt = (char*)Wt4;

    const int tid = threadIdx.x;
    const int wid = tid >> 6;
    const int lane = tid & 63;
    const int ln15 = lane & 15;
    const int kb16 = (lane >> 4) * 16;
    const int n0 = blockIdx.x * 64;
    const int rA = wid * 16 + ln15;
    const int rsw = (rA & 7) << 4;

    if (tid < 128) { bias[tid] = b1[tid]; s_sum[tid] = 0.0f; s_sq[tid] = 0.0f; }

    f32x4 acc[8];
#pragma unroll
    for (int i = 0; i < 8; ++i) acc[i] = (f32x4){0.0f, 0.0f, 0.0f, 0.0f};

    for (int c = 0; c < 6; ++c) {
        const int koff = (c & 1) * 64;
        __syncthreads();
        if (c < 2) {
#pragma unroll
            for (int i = 0; i < 2; ++i) {
                int g = tid + i * 256;
                int r = g >> 3, k8 = g & 7;
                int n = n0 + r;
                f32x4 v0 = {0.f, 0.f, 0.f, 0.f}, v1 = v0;
                if (n < N_NODES) {
                    const f32x4* p = reinterpret_cast<const f32x4*>(x + n * DIM + koff + k8 * 8);
                    v0 = __builtin_nontemporal_load(p);
                    v1 = __builtin_nontemporal_load(p + 1);
                }
                ushort_t pk[8] = {(ushort_t)f2bf(v0[0]), (ushort_t)f2bf(v0[1]),
                                  (ushort_t)f2bf(v0[2]), (ushort_t)f2bf(v0[3]),
                                  (ushort_t)f2bf(v1[0]), (ushort_t)f2bf(v1[1]),
                                  (ushort_t)f2bf(v1[2]), (ushort_t)f2bf(v1[3])};
                *(uint4*)(rowsA + ((r * 128 + k8 * 16) ^ ((r & 7) << 4))) = *(const uint4*)pk;
            }
        } else {
            const ushort_t* src16 = (c < 4) ? fwd : bwd;
#pragma unroll
            for (int i = 0; i < 2; ++i) {
                int g = tid + i * 256;
                int r = g >> 3, k8 = g & 7;
                int n = n0 + r;
                uint4 v = make_uint4(0u, 0u, 0u, 0u);
                if (n < N_NODES) v = *reinterpret_cast<const uint4*>(src16 + n * DIM + koff + k8 * 8);
                *(uint4*)(rowsA + ((r * 128 + k8 * 16) ^ ((r & 7) << 4))) = v;
            }
        }
#pragma unroll
        for (int i = 0; i < 4; ++i) {
            int g = tid + i * 256;
            int j = g >> 3, k8 = g & 7;
            uint4 w = *reinterpret_cast<const uint4*>(W1t + j * 384 + c * 64 + k8 * 8);
            *(uint4*)(Wt + ((j * 128 + k8 * 16) ^ ((j & 7) << 4))) = w;
        }
        __syncthreads();
#pragma unroll
        for (int ks = 0; ks < 2; ++ks) {
            bf16x8 a = *(bf16x8*)(rowsA + ((rA * 128 + ks * 64 + kb16) ^ rsw));
#pragma unroll
            for (int ct = 0; ct < 8; ++ct) {
                int j = ct * 16 + ln15;
                bf16x8 b = *(bf16x8*)(Wt + ((j * 128 + ks * 64 + kb16) ^ ((j & 7) << 4)));
                acc[ct] = __builtin_amdgcn_mfma_f32_16x16x32_bf16(a, b, acc[ct], 0, 0, 0);
            }
        }
    }
    __syncthreads();
    const int jcol = ln15;
#pragma unroll
    for (int ct = 0; ct < 8; ++ct) {
        int j = ct * 16 + jcol;
        float bj = bias[j];
        float s = 0.0f, q = 0.0f;
#pragma unroll
        for (int r = 0; r < 4; ++r) {
            int n = n0 + wid * 16 + (lane >> 4) * 4 + r;
            if (n < N_NODES) {
                float v = acc[ct][r] + bj;
                h1b[n * DIM + j] = (ushort_t)f2bf(v);
                s += v; q += v * v;
            }
        }
        s += __shfl_xor(s, 16); s += __shfl_xor(s, 32);
        q += __shfl_xor(q, 16); q += __shfl_xor(q, 32);
        if ((lane >> 4) == 0) { atomicAdd(&s_sum[j], s); atomicAdd(&s_sq[j], q); }
    }
    __syncthreads();
    if (tid < 128) {
        atomicAdd(&stats[tid], s_sum[tid]);
        atomicAdd(&stats[128 + tid], s_sq[tid]);
    }
}

// ---------------- E: h1 = relu(BN1(h1b)); h2b = bf16(h1 @ W2 + b2); col stats2 ----------------
__global__ __launch_bounds__(256) void k_gemm2(const ushort_t* __restrict__ h1b,
                                               const ushort_t* __restrict__ W2t,
                                               const float* __restrict__ b2,
                                               const float* __restrict__ g1,
                                               const float* __restrict__ be1,
                                               ushort_t* __restrict__ h2b,
                                               float* __restrict__ stats) {
    __shared__ uint4 rowsA4[512];
    __shared__ uint4 Wt4[1024];
    __shared__ float bias[128];
    __shared__ float ssc[128], ssh[128];
    __shared__ float s_sum[128], s_sq[128];
    char* rowsA = (char*)rowsA4;
    char* Wt = (char*)Wt4;

    const int tid = threadIdx.x;
    const int wid = tid >> 6;
    const int lane = tid & 63;
    const int ln15 = lane & 15;
    const int kb16 = (lane >> 4) * 16;
    const int n0 = blockIdx.x * 64;
    const int rA = wid * 16 + ln15;
    const int rsw = (rA & 7) << 4;

    if (tid < 128) {
        float mu = stats[tid] * (1.0f / N_NODES);
        float var = stats[128 + tid] * (1.0f / N_NODES) - mu * mu;
        float sc = rsqrtf(var + EPS) * g1[tid];
        ssc[tid] = sc;
        ssh[tid] = be1[tid] - mu * sc;
        bias[tid] = b2[tid];
        s_sum[tid] = 0.0f; s_sq[tid] = 0.0f;
    }

    f32x4 acc[8];
#pragma unroll
    for (int i = 0; i < 8; ++i) acc[i] = (f32x4){0.0f, 0.0f, 0.0f, 0.0f};

    for (int c = 0; c < 2; ++c) {
        const int koff = c * 64;
        __syncthreads();
#pragma unroll
        for (int i = 0; i < 2; ++i) {
            int g = tid + i * 256;
            int r = g >> 3, k8 = g & 7;
            int n = n0 + r;
            ushort_t pk[8] = {0, 0, 0, 0, 0, 0, 0, 0};
            if (n < N_NODES) {
                uint4 raw = *reinterpret_cast<const uint4*>(h1b + n * DIM + koff + k8 * 8);
                const ushort_t* rp = (const ushort_t*)&raw;
#pragma unroll
                for (int t = 0; t < 8; ++t) {
                    int kk = koff + k8 * 8 + t;
                    float v = fmaxf(bf2f(rp[t]) * ssc[kk] + ssh[kk], 0.0f);
                    pk[t] = (ushort_t)f2bf(v);
                }
            }
            *(uint4*)(rowsA + ((r * 128 + k8 * 16) ^ ((r & 7) << 4))) = *(const uint4*)pk;
        }
#pragma unroll
        for (int i = 0; i < 4; ++i) {
            int g = tid + i * 256;
            int j = g >> 3, k8 = g & 7;
            uint4 w = *reinterpret_cast<const uint4*>(W2t + j * 128 + c * 64 + k8 * 8);
            *(uint4*)(Wt + ((j * 128 + k8 * 16) ^ ((j & 7) << 4))) = w;
        }
        __syncthreads();
#pragma unroll
        for (int ks = 0; ks < 2; ++ks) {
            bf16x8 a = *(bf16x8*)(rowsA + ((rA * 128 + ks * 64 + kb16) ^ rsw));
#pragma unroll
            for (int ct = 0; ct < 8; ++ct) {
                int j = ct * 16 + ln15;
                bf16x8 b = *(bf16x8*)(Wt + ((j * 128 + ks * 64 + kb16) ^ ((j & 7) << 4)));
                acc[ct] = __builtin_amdgcn_mfma_f32_16x16x32_bf16(a, b, acc[ct], 0, 0, 0);
            }
        }
    }
    __syncthreads();
    const int jcol = ln15;
#pragma unroll
    for (int ct = 0; ct < 8; ++ct) {
        int j = ct * 16 + jcol;
        float bj = bias[j];
        float s = 0.0f, q = 0.0f;
#pragma unroll
        for (int r = 0; r < 4; ++r) {
            int n = n0 + wid * 16 + (lane >> 4) * 4 + r;
            if (n < N_NODES) {
                float v = acc[ct][r] + bj;
                h2b[n * DIM + j] = (ushort_t)f2bf(v);
                s += v; q += v * v;
            }
        }
        s += __shfl_xor(s, 16); s += __shfl_xor(s, 32);
        q += __shfl_xor(q, 16); q += __shfl_xor(q, 32);
        if ((lane >> 4) == 0) { atomicAdd(&s_sum[j], s); atomicAdd(&s_sq[j], q); }
    }
    __syncthreads();
    if (tid < 128) {
        atomicAdd(&stats[256 + tid], s_sum[tid]);
        atomicAdd(&stats[384 + tid], s_sq[tid]);
    }
}

// ---------------- F: h = relu(BN2(h2b)) -> out; att = sigmoid(h @ Wa + ba) ----------------
__global__ __launch_bounds__(256) void k_final(const ushort_t* __restrict__ h2b,
                                               const float* __restrict__ stats,
                                               const float* __restrict__ g2,
                                               const float* __restrict__ be2,
                                               const float* __restrict__ Wa,
                                               const float* __restrict__ ba,
                                               float* __restrict__ out) {
    const int lane = threadIdx.x & 63;
    const int wv = threadIdx.x >> 6;
    const int n = blockIdx.x * 4 + wv;
    if (n >= N_NODES) return;
    const int j0 = lane, j1 = lane + 64;

    float mu0 = stats[256 + j0] * (1.0f / N_NODES);
    float var0 = stats[384 + j0] * (1.0f / N_NODES) - mu0 * mu0;
    float sc0 = rsqrtf(var0 + EPS) * g2[j0];
    float sh0 = be2[j0] - mu0 * sc0;
    float mu1 = stats[256 + j1] * (1.0f / N_NODES);
    float var1 = stats[384 + j1] * (1.0f / N_NODES) - mu1 * mu1;
    float sc1 = rsqrtf(var1 + EPS) * g2[j1];
    float sh1 = be2[j1] - mu1 * sc1;

    float v0 = fmaxf(bf2f(h2b[n * DIM + j0]) * sc0 + sh0, 0.0f);
    float v1 = fmaxf(bf2f(h2b[n * DIM + j1]) * sc1 + sh1, 0.0f);
    out[n * DIM + j0] = v0;
    out[n * DIM + j1] = v1;

    float p = v0 * Wa[j0] + v1 * Wa[j1];
#pragma unroll
    for (int off = 32; off > 0; off >>= 1) p += __shfl_down(p, off);
    if (lane == 0) out[N_NODES * DIM + n] = 1.0f / (1.0f + expf(-(p + ba[0])));
}

extern "C" void kernel_launch(void* const* d_in, const int* in_sizes, int n_in,
                              void* d_out, int out_size, void* d_ws, size_t ws_size,
                              hipStream_t stream) {
    const float* x   = (const float*)d_in[0];
    const float* msg = (const float*)d_in[1];
    const float* W1  = (const float*)d_in[2];
    const float* b1  = (const float*)d_in[3];
    const float* g1  = (const float*)d_in[4];
    const float* be1 = (const float*)d_in[5];
    const float* W2  = (const float*)d_in[6];
    const float* b2  = (const float*)d_in[7];
    const float* g2  = (const float*)d_in[8];
    const float* be2 = (const float*)d_in[9];
    const float* Wa  = (const float*)d_in[10];
    const float* ba  = (const float*)d_in[11];
    const int*   ei  = (const int*)d_in[12];

    float*    stats = (float*)d_ws;                          // 512 f
    ushort_t* fwdb  = (ushort_t*)(stats + 512);              // N*128 bf16
    ushort_t* bwdb  = fwdb + N_NODES * DIM;                  // N*128 bf16
    int*      cnt   = (int*)(bwdb + N_NODES * DIM);          // 2N
    int*      slots = cnt + 2 * N_NODES;                     // 2N*CAP (38.4 MB)
    ushort_t* W1t   = (ushort_t*)(slots + 2 * N_NODES * CAP);
    ushort_t* W2t   = W1t + 128 * 384;
    u32x2*    msgb  = (u32x2*)(W2t + 128 * 128 + 128);       // E*128 bf16 (409.6 MB)

    ushort_t* h1b = (ushort_t*)d_out;                        // 12.8 MB scratch in out buffer
    ushort_t* h2b = fwdb;                                    // fwd dead after gemm1
    float*    out = (float*)d_out;

    k_prep<<<(2 * N_NODES + 255) / 256, 256, 0, stream>>>(W1, W2, W1t, W2t, stats, cnt);
    k_bucketconv<<<2 * CONVB, 256, 0, stream>>>(ei, cnt, slots, (const f32x4*)msg, msgb);
    k_gather<<<(2 * N_NODES) / 4, 256, 0, stream>>>(msgb, slots, cnt, fwdb, bwdb);
    k_gemm1<<<(N_NODES + 63) / 64, 256, 0, stream>>>(x, fwdb, bwdb, W1t, b1, h1b, stats);
    k_gemm2<<<(N_NODES + 63) / 64, 256, 0, stream>>>(h1b, W2t, b2, g1, be1, h2b, stats);
    k_final<<<(N_NODES + 3) / 4, 256, 0, stream>>>(h2b, stats, g2, be2, Wa, ba, out);
}

// Round 14
// 572.764 us; speedup vs baseline: 1.0933x; 1.0933x over previous
//
#include <hip/hip_runtime.h>
#include <math.h>

#define N_NODES 50000
#define N_EDGES 1600000
#define DIM 128          // D == H == 128
#define EPS 1e-5f
#define CAP 96           // bucket capacity; P(Poisson(32) >= 96) ~ 1e-18/bucket
#define CONVB 2048       // convert blocks in the specialized kernel

typedef short bf16x8 __attribute__((ext_vector_type(8)));
typedef float f32x4 __attribute__((ext_vector_type(4)));
typedef int i32x4 __attribute__((ext_vector_type(4)));
typedef unsigned int u32x2 __attribute__((ext_vector_type(2)));
typedef unsigned short ushort_t;

// fp32 -> bf16 round-to-nearest-even
__device__ __forceinline__ unsigned int f2bf(float f) {
    unsigned int u = __float_as_uint(f);
    return (u + 0x7FFFu + ((u >> 16) & 1u)) >> 16;
}
__device__ __forceinline__ float bf2f(ushort_t u) {
    return __uint_as_float(((unsigned int)u) << 16);
}
// unpack a word of 2 bf16 and max into (lo, hi) floats
__device__ __forceinline__ void wmax(unsigned int w, float& lo, float& hi) {
    lo = fmaxf(lo, __uint_as_float(w << 16));
    hi = fmaxf(hi, __uint_as_float(w & 0xFFFF0000u));
}

// ---------------- A: W1 -> W1t bf16 [128j][384k]; W2 -> W2t bf16 [128j][128k] ----------------
__global__ __launch_bounds__(256) void k_prep(const float* __restrict__ W1, const float* __restrict__ W2,
                                              ushort_t* __restrict__ W1t, ushort_t* __restrict__ W2t) {
    int gid = blockIdx.x * 256 + threadIdx.x;
    if (gid < 128 * 384) {
        int j = gid / 384, k = gid % 384;
        W1t[gid] = (ushort_t)f2bf(W1[k * 128 + j]);
    } else {
        int g2 = gid - 128 * 384;
        if (g2 < 128 * 128) {
            int j = g2 / 128, k = g2 % 128;
            W2t[g2] = (ushort_t)f2bf(W2[k * 128 + j]);
        }
    }
}

// ---------------- B: BLOCK-SPECIALIZED bucket (odd blocks) + convert (even blocks) ----------------
// Latency-bound binning and BW-bound convert co-resident -> true overlap.
__global__ __launch_bounds__(256) void k_bucketconv(const int* __restrict__ ei, int* __restrict__ cnt,
                                                    int* __restrict__ slots,
                                                    const f32x4* __restrict__ msg,
                                                    u32x2* __restrict__ msgb) {
    const int b = blockIdx.x;
    if (b & 1) {
        // ---- binning: odd blocks
        int t = (b >> 1) * 256 + threadIdx.x;
        if (t >= N_EDGES / 4) return;
        int4 r4 = reinterpret_cast<const int4*>(ei)[t];
        int4 c4 = reinterpret_cast<const int4*>(ei + N_EDGES)[t];
        int e = t * 4;
        slots[c4.x * CAP + atomicAdd(&cnt[c4.x], 1)] = e + 0;
        slots[c4.y * CAP + atomicAdd(&cnt[c4.y], 1)] = e + 1;
        slots[c4.z * CAP + atomicAdd(&cnt[c4.z], 1)] = e + 2;
        slots[c4.w * CAP + atomicAdd(&cnt[c4.w], 1)] = e + 3;
        slots[(N_NODES + r4.x) * CAP + atomicAdd(&cnt[N_NODES + r4.x], 1)] = e + 0;
        slots[(N_NODES + r4.y) * CAP + atomicAdd(&cnt[N_NODES + r4.y], 1)] = e + 1;
        slots[(N_NODES + r4.z) * CAP + atomicAdd(&cnt[N_NODES + r4.z], 1)] = e + 2;
        slots[(N_NODES + r4.w) * CAP + atomicAdd(&cnt[N_NODES + r4.w], 1)] = e + 3;
    } else {
        // ---- convert: even blocks (streaming, coalesced)
        const int cb = b >> 1;
        const size_t total = (size_t)N_EDGES * 32;   // f32x4 vectors
        const size_t stride = (size_t)CONVB * 256;
        for (size_t v = (size_t)cb * 256 + threadIdx.x; v < total; v += stride) {
            f32x4 m = __builtin_nontemporal_load(&msg[v]);
            u32x2 o;
            o[0] = f2bf(m[0]) | (f2bf(m[1]) << 16);
            o[1] = f2bf(m[2]) | (f2bf(m[3]) << 16);
            msgb[v] = o;   // regular store: leave lines in L2/L3 for the gather
        }
    }
}

// ---------------- C: gather-max over bf16 rows; 8 rows in flight per half-wave ----------------
__global__ __launch_bounds__(256) void k_gather(const u32x2* __restrict__ msgb,
                                                const int* __restrict__ slots,
                                                const int* __restrict__ cnt,
                                                ushort_t* __restrict__ fwd,
                                                ushort_t* __restrict__ bwd) {
    const int wid = blockIdx.x * 4 + (threadIdx.x >> 6);   // 0 .. 2N-1
    const int dir = wid & 1;                               // interleave fwd/bwd in time
    const int n = wid >> 1;
    const int lane = threadIdx.x & 63;
    const int q = lane & 31;        // channel quad: channels q*4..q*4+3 (one u32x2)
    const int h = lane >> 5;        // half-wave id
    const int c = cnt[dir * N_NODES + n];
    const int* el = slots + (size_t)(dir * N_NODES + n) * CAP;

    float l0a = -INFINITY, h0a = -INFINITY, l1a = -INFINITY, h1a = -INFINITY;
    float l0b = -INFINITY, h0b = -INFINITY, l1b = -INFINITY, h1b = -INFINITY;
    const int nfull = c >> 2;
    int g = h;
    // 2 groups (8 rows) in flight per half-wave
    for (; g + 2 < nfull; g += 4) {
        i32x4 ea = *reinterpret_cast<const i32x4*>(el + g * 4);
        i32x4 eb = *reinterpret_cast<const i32x4*>(el + (g + 2) * 4);
        u32x2 m0 = msgb[(size_t)ea[0] * 32 + q];
        u32x2 m1 = msgb[(size_t)ea[1] * 32 + q];
        u32x2 m2 = msgb[(size_t)ea[2] * 32 + q];
        u32x2 m3 = msgb[(size_t)ea[3] * 32 + q];
        u32x2 m4 = msgb[(size_t)eb[0] * 32 + q];
        u32x2 m5 = msgb[(size_t)eb[1] * 32 + q];
        u32x2 m6 = msgb[(size_t)eb[2] * 32 + q];
        u32x2 m7 = msgb[(size_t)eb[3] * 32 + q];
        wmax(m0[0], l0a, h0a); wmax(m0[1], l1a, h1a);
        wmax(m1[0], l0a, h0a); wmax(m1[1], l1a, h1a);
        wmax(m2[0], l0a, h0a); wmax(m2[1], l1a, h1a);
        wmax(m3[0], l0a, h0a); wmax(m3[1], l1a, h1a);
        wmax(m4[0], l0b, h0b); wmax(m4[1], l1b, h1b);
        wmax(m5[0], l0b, h0b); wmax(m5[1], l1b, h1b);
        wmax(m6[0], l0b, h0b); wmax(m6[1], l1b, h1b);
        wmax(m7[0], l0b, h0b); wmax(m7[1], l1b, h1b);
    }
    for (; g < nfull; g += 2) {
        i32x4 e4 = *reinterpret_cast<const i32x4*>(el + g * 4);
        u32x2 m0 = msgb[(size_t)e4[0] * 32 + q];
        u32x2 m1 = msgb[(size_t)e4[1] * 32 + q];
        u32x2 m2 = msgb[(size_t)e4[2] * 32 + q];
        u32x2 m3 = msgb[(size_t)e4[3] * 32 + q];
        wmax(m0[0], l0a, h0a); wmax(m0[1], l1a, h1a);
        wmax(m1[0], l0a, h0a); wmax(m1[1], l1a, h1a);
        wmax(m2[0], l0a, h0a); wmax(m2[1], l1a, h1a);
        wmax(m3[0], l0a, h0a); wmax(m3[1], l1a, h1a);
    }
    if (h == (nfull & 1)) {
        for (int p = nfull * 4; p < c; ++p) {
            u32x2 m = msgb[(size_t)el[p] * 32 + q];
            wmax(m[0], l0b, h0b); wmax(m[1], l1b, h1b);
        }
    }
    float l0 = fmaxf(l0a, l0b), h0 = fmaxf(h0a, h0b);
    float l1 = fmaxf(l1a, l1b), h1 = fmaxf(h1a, h1b);
    l0 = fmaxf(l0, __shfl_xor(l0, 32));
    h0 = fmaxf(h0, __shfl_xor(h0, 32));
    l1 = fmaxf(l1, __shfl_xor(l1, 32));
    h1 = fmaxf(h1, __shfl_xor(h1, 32));

    if (h == 0) {
        u32x2 o;
        if (c == 0) { o[0] = 0u; o[1] = 0u; }   // empty segment -> 0
        else {
            o[0] = (__float_as_uint(l0) >> 16) | (__float_as_uint(h0) & 0xFFFF0000u);
            o[1] = (__float_as_uint(l1) >> 16) | (__float_as_uint(h1) & 0xFFFF0000u);
        }
        *reinterpret_cast<u32x2*>((dir ? bwd : fwd) + n * DIM + q * 4) = o;
    }
}

// ======== MFMA GEMM core (64 rows x 128 cols per block, 4 waves, 16x16x32 bf16) ========
// LDS tiles XOR-swizzled: byte ^= ((row&7)<<4).

// ---------------- D: h1b = bf16([x|fwd|bwd] @ W1 + b1), col stats ----------------
__global__ __launch_bounds__(256) void k_gemm1(const float* __restrict__ x,
                                               const ushort_t* __restrict__ fwd,
                                               const ushort_t* __restrict__ bwd,
                                               const ushort_t* __restrict__ W1t,
                                               const float* __restrict__ b1,
                                               ushort_t* __restrict__ h1b,
                                               float* __restrict__ stats) {
    __shared__ uint4 rowsA4[512];      // 64 rows x 64 k bf16 (8 KB), swizzled
    __shared__ uint4 Wt4[1024];        // 128 j x 64 k bf16 (16 KB), swizzled
    __shared__ float bias[128];
    __shared__ float s_sum[128], s_sq[128];
    char* rowsA = (char*)rowsA4;
    char* Wt = (char*)Wt4;

    const int tid = threadIdx.x;
    const int wid = tid >> 6;
    const int lane = tid & 63;
    const int ln15 = lane & 15;
    const int kb16 = (lane >> 4) * 16;
    const int n0 = blockIdx.x * 64;
    const int rA = wid * 16 + ln15;
    const int rsw = (rA & 7) << 4;

    if (tid < 128) { bias[tid] = b1[tid]; s_sum[tid] = 0.0f; s_sq[tid] = 0.0f; }

    f32x4 acc[8];
#pragma unroll
    for (int i = 0; i < 8; ++i) acc[i] = (f32x4){0.0f, 0.0f, 0.0f, 0.0f};

    for (int c = 0; c < 6; ++c) {
        const int koff = (c & 1) * 64;
        __syncthreads();
        if (c < 2) {
#pragma unroll
            for (int i = 0; i < 2; ++i) {
                int g = tid + i * 256;
                int r = g >> 3, k8 = g & 7;
                int n = n0 + r;
                f32x4 v0 = {0.f, 0.f, 0.f, 0.f}, v1 = v0;
                if (n < N_NODES) {
                    const f32x4* p = reinterpret_cast<const f32x4*>(x + n * DIM + koff + k8 * 8);
                    v0 = __builtin_nontemporal_load(p);
                    v1 = __builtin_nontemporal_load(p + 1);
                }
                ushort_t pk[8] = {(ushort_t)f2bf(v0[0]), (ushort_t)f2bf(v0[1]),
                                  (ushort_t)f2bf(v0[2]), (ushort_t)f2bf(v0[3]),
                                  (ushort_t)f2bf(v1[0]), (ushort_t)f2bf(v1[1]),
                                  (ushort_t)f2bf(v1[2]), (ushort_t)f2bf(v1[3])};
                *(uint4*)(rowsA + ((r * 128 + k8 * 16) ^ ((r & 7) << 4))) = *(const uint4*)pk;
            }
        } else {
            const ushort_t* src16 = (c < 4) ? fwd : bwd;
#pragma unroll
            for (int i = 0; i < 2; ++i) {
                int g = tid + i * 256;
                int r = g >> 3, k8 = g & 7;
                int n = n0 + r;
                uint4 v = make_uint4(0u, 0u, 0u, 0u);
                if (n < N_NODES) v = *reinterpret_cast<const uint4*>(src16 + n * DIM + koff + k8 * 8);
                *(uint4*)(rowsA + ((r * 128 + k8 * 16) ^ ((r & 7) << 4))) = v;
            }
        }
#pragma unroll
        for (int i = 0; i < 4; ++i) {
            int g = tid + i * 256;
            int j = g >> 3, k8 = g & 7;
            uint4 w = *reinterpret_cast<const uint4*>(W1t + j * 384 + c * 64 + k8 * 8);
            *(uint4*)(Wt + ((j * 128 + k8 * 16) ^ ((j & 7) << 4))) = w;
        }
        __syncthreads();
#pragma unroll
        for (int ks = 0; ks < 2; ++ks) {
            bf16x8 a = *(bf16x8*)(rowsA + ((rA * 128 + ks * 64 + kb16) ^ rsw));
#pragma unroll
            for (int ct = 0; ct < 8; ++ct) {
                int j = ct * 16 + ln15;
                bf16x8 b = *(bf16x8*)(Wt + ((j * 128 + ks * 64 + kb16) ^ ((j & 7) << 4)));
                acc[ct] = __builtin_amdgcn_mfma_f32_16x16x32_bf16(a, b, acc[ct], 0, 0, 0);
            }
        }
    }
    __syncthreads();
    const int jcol = ln15;
#pragma unroll
    for (int ct = 0; ct < 8; ++ct) {
        int j = ct * 16 + jcol;
        float bj = bias[j];
        float s = 0.0f, q = 0.0f;
#pragma unroll
        for (int r = 0; r < 4; ++r) {
            int n = n0 + wid * 16 + (lane >> 4) * 4 + r;
            if (n < N_NODES) {
                float v = acc[ct][r] + bj;
                h1b[n * DIM + j] = (ushort_t)f2bf(v);
                s += v; q += v * v;
            }
        }
        s += __shfl_xor(s, 16); s += __shfl_xor(s, 32);
        q += __shfl_xor(q, 16); q += __shfl_xor(q, 32);
        if ((lane >> 4) == 0) { atomicAdd(&s_sum[j], s); atomicAdd(&s_sq[j], q); }
    }
    __syncthreads();
    if (tid < 128) {
        atomicAdd(&stats[tid], s_sum[tid]);
        atomicAdd(&stats[128 + tid], s_sq[tid]);
    }
}

// ---------------- E: h1 = relu(BN1(h1b)); h2b = bf16(h1 @ W2 + b2); col stats2 ----------------
__global__ __launch_bounds__(256) void k_gemm2(const ushort_t* __restrict__ h1b,
                                               const ushort_t* __restrict__ W2t,
                                               const float* __restrict__ b2,
                                               const float* __restrict__ g1,
                                               const float* __restrict__ be1,
                                               ushort_t* __restrict__ h2b,
                                               float* __restrict__ stats) {
    __shared__ uint4 rowsA4[512];
    __shared__ uint4 Wt4[1024];
    __shared__ float bias[128];
    __shared__ float ssc[128], ssh[128];
    __shared__ float s_sum[128], s_sq[128];
    char* rowsA = (char*)rowsA4;
    char* Wt = (char*)Wt4;

    const int tid = threadIdx.x;
    const int wid = tid >> 6;
    const int lane = tid & 63;
    const int ln15 = lane & 15;
    const int kb16 = (lane >> 4) * 16;
    const int n0 = blockIdx.x * 64;
    const int rA = wid * 16 + ln15;
    const int rsw = (rA & 7) << 4;

    if (tid < 128) {
        float mu = stats[tid] * (1.0f / N_NODES);
        float var = stats[128 + tid] * (1.0f / N_NODES) - mu * mu;
        float sc = rsqrtf(var + EPS) * g1[tid];
        ssc[tid] = sc;
        ssh[tid] = be1[tid] - mu * sc;
        bias[tid] = b2[tid];
        s_sum[tid] = 0.0f; s_sq[tid] = 0.0f;
    }

    f32x4 acc[8];
#pragma unroll
    for (int i = 0; i < 8; ++i) acc[i] = (f32x4){0.0f, 0.0f, 0.0f, 0.0f};

    for (int c = 0; c < 2; ++c) {
        const int koff = c * 64;
        __syncthreads();
#pragma unroll
        for (int i = 0; i < 2; ++i) {
            int g = tid + i * 256;
            int r = g >> 3, k8 = g & 7;
            int n = n0 + r;
            ushort_t pk[8] = {0, 0, 0, 0, 0, 0, 0, 0};
            if (n < N_NODES) {
                uint4 raw = *reinterpret_cast<const uint4*>(h1b + n * DIM + koff + k8 * 8);
                const ushort_t* rp = (const ushort_t*)&raw;
#pragma unroll
                for (int t = 0; t < 8; ++t) {
                    int kk = koff + k8 * 8 + t;
                    float v = fmaxf(bf2f(rp[t]) * ssc[kk] + ssh[kk], 0.0f);
                    pk[t] = (ushort_t)f2bf(v);
                }
            }
            *(uint4*)(rowsA + ((r * 128 + k8 * 16) ^ ((r & 7) << 4))) = *(const uint4*)pk;
        }
#pragma unroll
        for (int i = 0; i < 4; ++i) {
            int g = tid + i * 256;
            int j = g >> 3, k8 = g & 7;
            uint4 w = *reinterpret_cast<const uint4*>(W2t + j * 128 + c * 64 + k8 * 8);
            *(uint4*)(Wt + ((j * 128 + k8 * 16) ^ ((j & 7) << 4))) = w;
        }
        __syncthreads();
#pragma unroll
        for (int ks = 0; ks < 2; ++ks) {
            bf16x8 a = *(bf16x8*)(rowsA + ((rA * 128 + ks * 64 + kb16) ^ rsw));
#pragma unroll
            for (int ct = 0; ct < 8; ++ct) {
                int j = ct * 16 + ln15;
                bf16x8 b = *(bf16x8*)(Wt + ((j * 128 + ks * 64 + kb16) ^ ((j & 7) << 4)));
                acc[ct] = __builtin_amdgcn_mfma_f32_16x16x32_bf16(a, b, acc[ct], 0, 0, 0);
            }
        }
    }
    __syncthreads();
    const int jcol = ln15;
#pragma unroll
    for (int ct = 0; ct < 8; ++ct) {
        int j = ct * 16 + jcol;
        float bj = bias[j];
        float s = 0.0f, q = 0.0f;
#pragma unroll
        for (int r = 0; r < 4; ++r) {
            int n = n0 + wid * 16 + (lane >> 4) * 4 + r;
            if (n < N_NODES) {
                float v = acc[ct][r] + bj;
                h2b[n * DIM + j] = (ushort_t)f2bf(v);
                s += v; q += v * v;
            }
        }
        s += __shfl_xor(s, 16); s += __shfl_xor(s, 32);
        q += __shfl_xor(q, 16); q += __shfl_xor(q, 32);
        if ((lane >> 4) == 0) { atomicAdd(&s_sum[j], s); atomicAdd(&s_sq[j], q); }
    }
    __syncthreads();
    if (tid < 128) {
        atomicAdd(&stats[256 + tid], s_sum[tid]);
        atomicAdd(&stats[384 + tid], s_sq[tid]);
    }
}

// ---------------- F: h = relu(BN2(h2b)) -> out; att = sigmoid(h @ Wa + ba) ----------------
__global__ __launch_bounds__(256) void k_final(const ushort_t* __restrict__ h2b,
                                               const float* __restrict__ stats,
                                               const float* __restrict__ g2,
                                               const float* __restrict__ be2,
                                               const float* __restrict__ Wa,
                                               const float* __restrict__ ba,
                                               float* __restrict__ out) {
    const int lane = threadIdx.x & 63;
    const int wv = threadIdx.x >> 6;
    const int n = blockIdx.x * 4 + wv;
    if (n >= N_NODES) return;
    const int j0 = lane, j1 = lane + 64;

    float mu0 = stats[256 + j0] * (1.0f / N_NODES);
    float var0 = stats[384 + j0] * (1.0f / N_NODES) - mu0 * mu0;
    float sc0 = rsqrtf(var0 + EPS) * g2[j0];
    float sh0 = be2[j0] - mu0 * sc0;
    float mu1 = stats[256 + j1] * (1.0f / N_NODES);
    float var1 = stats[384 + j1] * (1.0f / N_NODES) - mu1 * mu1;
    float sc1 = rsqrtf(var1 + EPS) * g2[j1];
    float sh1 = be2[j1] - mu1 * sc1;

    float v0 = fmaxf(bf2f(h2b[n * DIM + j0]) * sc0 + sh0, 0.0f);
    float v1 = fmaxf(bf2f(h2b[n * DIM + j1]) * sc1 + sh1, 0.0f);
    out[n * DIM + j0] = v0;
    out[n * DIM + j1] = v1;

    float p = v0 * Wa[j0] + v1 * Wa[j1];
#pragma unroll
    for (int off = 32; off > 0; off >>= 1) p += __shfl_down(p, off);
    if (lane == 0) out[N_NODES * DIM + n] = 1.0f / (1.0f + expf(-(p + ba[0])));
}

extern "C" void kernel_launch(void* const* d_in, const int* in_sizes, int n_in,
                              void* d_out, int out_size, void* d_ws, size_t ws_size,
                              hipStream_t stream) {
    const float* x   = (const float*)d_in[0];
    const float* msg = (const float*)d_in[1];
    const float* W1  = (const float*)d_in[2];
    const float* b1  = (const float*)d_in[3];
    const float* g1  = (const float*)d_in[4];
    const float* be1 = (const float*)d_in[5];
    const float* W2  = (const float*)d_in[6];
    const float* b2  = (const float*)d_in[7];
    const float* g2  = (const float*)d_in[8];
    const float* be2 = (const float*)d_in[9];
    const float* Wa  = (const float*)d_in[10];
    const float* ba  = (const float*)d_in[11];
    const int*   ei  = (const int*)d_in[12];

    float*    stats = (float*)d_ws;                          // 512 f
    ushort_t* fwdb  = (ushort_t*)(stats + 512);              // N*128 bf16
    ushort_t* bwdb  = fwdb + N_NODES * DIM;                  // N*128 bf16
    int*      cnt   = (int*)(bwdb + N_NODES * DIM);          // 2N
    int*      slots = cnt + 2 * N_NODES;                     // 2N*CAP (38.4 MB)
    ushort_t* W1t   = (ushort_t*)(slots + 2 * N_NODES * CAP);
    ushort_t* W2t   = W1t + 128 * 384;
    u32x2*    msgb  = (u32x2*)(W2t + 128 * 128 + 128);       // E*128 bf16 (409.6 MB)

    ushort_t* h1b = (ushort_t*)d_out;                        // 12.8 MB scratch in out buffer
    ushort_t* h2b = fwdb;                                    // fwd dead after gemm1
    float*    out = (float*)d_out;

    (void)hipMemsetAsync(stats, 0, 512 * sizeof(float), stream);
    (void)hipMemsetAsync(cnt, 0, 2 * N_NODES * sizeof(int), stream);
    k_prep<<<(128 * 384 + 128 * 128 + 255) / 256, 256, 0, stream>>>(W1, W2, W1t, W2t);
    k_bucketconv<<<2 * CONVB, 256, 0, stream>>>(ei, cnt, slots, (const f32x4*)msg, msgb);
    k_gather<<<(2 * N_NODES) / 4, 256, 0, stream>>>(msgb, slots, cnt, fwdb, bwdb);
    k_gemm1<<<(N_NODES + 63) / 64, 256, 0, stream>>>(x, fwdb, bwdb, W1t, b1, h1b, stats);
    k_gemm2<<<(N_NODES + 63) / 64, 256, 0, stream>>>(h1b, W2t, b2, g1, be1, h2b, stats);
    k_final<<<(N_NODES + 3) / 4, 256, 0, stream>>>(h2b, stats, g2, be2, Wa, ba, out);
}